// Round 1
// baseline (479.993 us; speedup 1.0000x reference)
//
#include <hip/hip_runtime.h>

#define S_LEN 8192
#define HID   1024
#define NHEAD 16
#define DH    64
#define WIN   128
#define NCHUNK (S_LEN / WIN)   // 64

typedef _Float16 half8   __attribute__((ext_vector_type(8)));
typedef _Float16 half4_t __attribute__((ext_vector_type(4)));
typedef float    f32x4   __attribute__((ext_vector_type(4)));

#define QPITCH 72    // sQ/sK row pitch in f16 elems (64 + 8 pad, keeps 16B align)
#define PPITCH 136   // sP/sVt row pitch in f16 elems (128 + 8 pad)

__global__ __launch_bounds__(256, 1)
void swa_fwd(const float* __restrict__ qg,
             const float* __restrict__ kg,
             const float* __restrict__ vg,
             float* __restrict__ og)
{
    const int c    = blockIdx.x;   // chunk
    const int h    = blockIdx.y;   // head
    const int b    = blockIdx.z;   // batch
    const int tid  = threadIdx.x;
    const int wave = tid >> 6;
    const int lane = tid & 63;
    const int l16  = lane & 15;
    const int quad = lane >> 4;

    __shared__ _Float16 sQ [128 * QPITCH];   // 18432 B
    __shared__ _Float16 sK [128 * QPITCH];   // 18432 B
    __shared__ _Float16 sVt[ 64 * PPITCH];   // 17408 B  (V transposed: [dim][key])
    __shared__ _Float16 sP [4 * 32 * PPITCH];// 34816 B  (wave-private P tiles)

    const size_t qbase  = (((size_t)b * S_LEN + (size_t)c * WIN) * HID) + (size_t)h * DH;
    const size_t kvbase = (((size_t)b * S_LEN) * HID) + (size_t)h * DH;

    // ---- stage Q chunk (128x64 f32 -> f16 LDS)
    {
        const int r0 = tid >> 4;
        const int c4 = (tid & 15) * 4;
        for (int p = 0; p < 8; ++p) {
            const int row = p * 16 + r0;
            const float4 f = *(const float4*)(qg + qbase + (size_t)row * HID + c4);
            half4_t hv = { (_Float16)f.x, (_Float16)f.y, (_Float16)f.z, (_Float16)f.w };
            *(half4_t*)&sQ[row * QPITCH + c4] = hv;
        }
    }

    f32x4 Oacc[2][4];
    float m_i[2][4], l_i[2][4];
    for (int mt = 0; mt < 2; ++mt)
        for (int r = 0; r < 4; ++r) { m_i[mt][r] = -3.0e38f; l_i[mt][r] = 0.0f; }
    for (int mt = 0; mt < 2; ++mt)
        for (int dt = 0; dt < 4; ++dt) Oacc[mt][dt] = (f32x4){0.f, 0.f, 0.f, 0.f};

    const int t0 = (c == 0)          ? 1 : 0;   // no left tile at sequence start
    const int t1 = (c == NCHUNK - 1) ? 1 : 2;   // no right tile at sequence end
    const float L2E = 1.44269504088896f;

    for (int t = t0; t <= t1; ++t) {
        __syncthreads();   // protect sK/sVt from previous iteration's readers
        // ---- stage K tile (key-major) and V tile (transposed) as f16
        {
            const int r0 = tid >> 4;
            const int c4 = (tid & 15) * 4;
            const size_t kb = kvbase + (size_t)(c * WIN + (t - 1) * WIN) * HID;
            for (int p = 0; p < 8; ++p) {
                const int row = p * 16 + r0;
                const float4 f = *(const float4*)(kg + kb + (size_t)row * HID + c4);
                half4_t hk = { (_Float16)f.x, (_Float16)f.y, (_Float16)f.z, (_Float16)f.w };
                *(half4_t*)&sK[row * QPITCH + c4] = hk;
                const float4 g = *(const float4*)(vg + kb + (size_t)row * HID + c4);
                sVt[(c4 + 0) * PPITCH + row] = (_Float16)g.x;
                sVt[(c4 + 1) * PPITCH + row] = (_Float16)g.y;
                sVt[(c4 + 2) * PPITCH + row] = (_Float16)g.z;
                sVt[(c4 + 3) * PPITCH + row] = (_Float16)g.w;
            }
        }
        __syncthreads();

        // ---- S = Q K^T  (per wave: 32 rows x 128 cols)
        f32x4 Sacc[2][8];
        for (int mt = 0; mt < 2; ++mt)
            for (int nt = 0; nt < 8; ++nt) Sacc[mt][nt] = (f32x4){0.f, 0.f, 0.f, 0.f};
        for (int kk = 0; kk < 2; ++kk) {
            half8 afr[2];
            afr[0] = *(const half8*)&sQ[(wave * 32 +  0 + l16) * QPITCH + kk * 32 + quad * 8];
            afr[1] = *(const half8*)&sQ[(wave * 32 + 16 + l16) * QPITCH + kk * 32 + quad * 8];
            for (int nt = 0; nt < 8; ++nt) {
                const half8 bfr = *(const half8*)&sK[(nt * 16 + l16) * QPITCH + kk * 32 + quad * 8];
                Sacc[0][nt] = __builtin_amdgcn_mfma_f32_16x16x32_f16(afr[0], bfr, Sacc[0][nt], 0, 0, 0);
                Sacc[1][nt] = __builtin_amdgcn_mfma_f32_16x16x32_f16(afr[1], bfr, Sacc[1][nt], 0, 0, 0);
            }
        }

        // ---- band mask + online softmax + P -> LDS (wave-private region)
        for (int mt = 0; mt < 2; ++mt) {
            const int ibase = wave * 32 + mt * 16 + quad * 4;  // query row of reg r is ibase+r
            if (t != 1) {
                for (int nt = 0; nt < 8; ++nt) {
                    const int j = nt * 16 + l16;               // key col (C/D: col = lane&15)
                    for (int r = 0; r < 4; ++r) {
                        const int i = ibase + r;
                        const bool valid = (t == 0) ? (j >= i) : (j <= i);
                        if (!valid) Sacc[mt][nt][r] = -3.0e38f;
                    }
                }
            }
            float mx[4];
            for (int r = 0; r < 4; ++r) {
                mx[r] = Sacc[mt][0][r];
                for (int nt = 1; nt < 8; ++nt) mx[r] = fmaxf(mx[r], Sacc[mt][nt][r]);
            }
            for (int off = 1; off < 16; off <<= 1)
                for (int r = 0; r < 4; ++r) mx[r] = fmaxf(mx[r], __shfl_xor(mx[r], off, 16));
            float alpha[4], rs[4];
            for (int r = 0; r < 4; ++r) {
                const float mnew = fmaxf(m_i[mt][r], mx[r]);
                alpha[r] = exp2f((m_i[mt][r] - mnew) * L2E);
                m_i[mt][r] = mnew;
                rs[r] = 0.0f;
            }
            _Float16* pw = &sP[(wave * 32 + mt * 16) * PPITCH];
            for (int nt = 0; nt < 8; ++nt) {
                for (int r = 0; r < 4; ++r) {
                    const float p = exp2f((Sacc[mt][nt][r] - m_i[mt][r]) * L2E);
                    rs[r] += p;
                    pw[(quad * 4 + r) * PPITCH + nt * 16 + l16] = (_Float16)p;
                }
            }
            for (int off = 1; off < 16; off <<= 1)
                for (int r = 0; r < 4; ++r) rs[r] += __shfl_xor(rs[r], off, 16);
            for (int r = 0; r < 4; ++r) l_i[mt][r] = l_i[mt][r] * alpha[r] + rs[r];
            for (int dt = 0; dt < 4; ++dt)
                for (int r = 0; r < 4; ++r) Oacc[mt][dt][r] *= alpha[r];
        }
        __syncthreads();   // drain sP writes (also keeps waves in step for sVt reuse)

        // ---- O += P V   (contraction over 128 keys, 4 k-steps of 32)
        for (int kk = 0; kk < 4; ++kk) {
            half8 afr[2];
            afr[0] = *(const half8*)&sP[(wave * 32 +  0 + l16) * PPITCH + kk * 32 + quad * 8];
            afr[1] = *(const half8*)&sP[(wave * 32 + 16 + l16) * PPITCH + kk * 32 + quad * 8];
            for (int dt = 0; dt < 4; ++dt) {
                const half8 bfr = *(const half8*)&sVt[(dt * 16 + l16) * PPITCH + kk * 32 + quad * 8];
                Oacc[0][dt] = __builtin_amdgcn_mfma_f32_16x16x32_f16(afr[0], bfr, Oacc[0][dt], 0, 0, 0);
                Oacc[1][dt] = __builtin_amdgcn_mfma_f32_16x16x32_f16(afr[1], bfr, Oacc[1][dt], 0, 0, 0);
            }
        }
    }

    // ---- epilogue: O / l, store fp32
    for (int mt = 0; mt < 2; ++mt) {
        for (int r = 0; r < 4; ++r) {
            const float inv = 1.0f / l_i[mt][r];
            const int row = wave * 32 + mt * 16 + quad * 4 + r;
            float* orow = og + qbase + (size_t)row * HID;
            for (int dt = 0; dt < 4; ++dt)
                orow[dt * 16 + l16] = Oacc[mt][dt][r] * inv;
        }
    }
}

extern "C" void kernel_launch(void* const* d_in, const int* in_sizes, int n_in,
                              void* d_out, int out_size, void* d_ws, size_t ws_size,
                              hipStream_t stream) {
    const float* q = (const float*)d_in[0];
    const float* k = (const float*)d_in[1];
    const float* v = (const float*)d_in[2];
    float* out = (float*)d_out;
    dim3 grid(NCHUNK, NHEAD, 2);   // (chunk, head, batch)
    dim3 block(256);
    swa_fwd<<<grid, block, 0, stream>>>(q, k, v, out);
}

// Round 2
// 352.795 us; speedup vs baseline: 1.3605x; 1.3605x over previous
//
#include <hip/hip_runtime.h>

#define S_LEN 8192
#define HID   1024
#define NHEAD 16
#define DH    64
#define WIN   128
#define NCHUNK (S_LEN / WIN)   // 64

typedef _Float16 half8   __attribute__((ext_vector_type(8)));
typedef _Float16 half4_t __attribute__((ext_vector_type(4)));
typedef float    f32x4   __attribute__((ext_vector_type(4)));

#define QPITCH 72    // sK row pitch in f16 elems (64 + 8 pad, keeps 16B align)
#define PPITCH 136   // sP/sVt row pitch in f16 elems (128 + 8 pad)

__global__ __launch_bounds__(256, 3)
void swa_fwd(const float* __restrict__ qg,
             const float* __restrict__ kg,
             const float* __restrict__ vg,
             float* __restrict__ og)
{
    const int c    = blockIdx.x;   // chunk
    const int h    = blockIdx.y;   // head
    const int b    = blockIdx.z;   // batch
    const int tid  = threadIdx.x;
    const int wave = tid >> 6;
    const int lane = tid & 63;
    const int l16  = lane & 15;
    const int quad = lane >> 4;

    __shared__ _Float16 sK [128 * QPITCH];   // 18432 B
    __shared__ _Float16 sVt[ 64 * PPITCH];   // 17408 B  (V transposed: [dim][key])
    __shared__ _Float16 sP [4 * 16 * PPITCH];// 17408 B  (wave-private, one mt at a time)
    // total 53248 B -> 3 blocks/CU

    const size_t qbase  = (((size_t)b * S_LEN + (size_t)c * WIN) * HID) + (size_t)h * DH;
    const size_t kvbase = (((size_t)b * S_LEN) * HID) + (size_t)h * DH;

    // ---- load this wave's Q rows directly into A-fragment registers (f32->f16)
    // A-frag for (mt,kk): row = wave*32 + mt*16 + l16, cols kk*32 + quad*8 .. +7
    half8 qf[2][2];
    for (int mt = 0; mt < 2; ++mt) {
        const int row = wave * 32 + mt * 16 + l16;
        const float* qrow = qg + qbase + (size_t)row * HID;
        for (int kk = 0; kk < 2; ++kk) {
            const float4 a = *(const float4*)(qrow + kk * 32 + quad * 8);
            const float4 d = *(const float4*)(qrow + kk * 32 + quad * 8 + 4);
            qf[mt][kk] = (half8){ (_Float16)a.x, (_Float16)a.y, (_Float16)a.z, (_Float16)a.w,
                                  (_Float16)d.x, (_Float16)d.y, (_Float16)d.z, (_Float16)d.w };
        }
    }

    f32x4 Oacc[2][4];
    float m_i[2][4], l_i[2][4];
    for (int mt = 0; mt < 2; ++mt)
        for (int r = 0; r < 4; ++r) { m_i[mt][r] = -3.0e38f; l_i[mt][r] = 0.0f; }
    for (int mt = 0; mt < 2; ++mt)
        for (int dt = 0; dt < 4; ++dt) Oacc[mt][dt] = (f32x4){0.f, 0.f, 0.f, 0.f};

    const int t0 = (c == 0)          ? 1 : 0;   // no left tile at sequence start
    const int t1 = (c == NCHUNK - 1) ? 1 : 2;   // no right tile at sequence end
    const float L2E = 1.44269504088896f;

    for (int t = t0; t <= t1; ++t) {
        __syncthreads();   // all waves done reading sK/sVt from previous tile
        // ---- stage K tile (key-major) and V tile (transposed) as f16
        {
            const int r0 = tid >> 4;
            const int c4 = (tid & 15) * 4;
            const size_t kb = kvbase + (size_t)(c * WIN + (t - 1) * WIN) * HID;
            for (int p = 0; p < 8; ++p) {
                const int row = p * 16 + r0;
                const float4 f = *(const float4*)(kg + kb + (size_t)row * HID + c4);
                half4_t hk = { (_Float16)f.x, (_Float16)f.y, (_Float16)f.z, (_Float16)f.w };
                *(half4_t*)&sK[row * QPITCH + c4] = hk;
                const float4 g = *(const float4*)(vg + kb + (size_t)row * HID + c4);
                sVt[(c4 + 0) * PPITCH + row] = (_Float16)g.x;
                sVt[(c4 + 1) * PPITCH + row] = (_Float16)g.y;
                sVt[(c4 + 2) * PPITCH + row] = (_Float16)g.z;
                sVt[(c4 + 3) * PPITCH + row] = (_Float16)g.w;
            }
        }
        __syncthreads();

        // ---- S = Q K^T  (per wave: 32 rows x 128 cols)
        f32x4 Sacc[2][8];
        for (int mt = 0; mt < 2; ++mt)
            for (int nt = 0; nt < 8; ++nt) Sacc[mt][nt] = (f32x4){0.f, 0.f, 0.f, 0.f};
        for (int kk = 0; kk < 2; ++kk) {
            for (int nt = 0; nt < 8; ++nt) {
                const half8 bfr = *(const half8*)&sK[(nt * 16 + l16) * QPITCH + kk * 32 + quad * 8];
                Sacc[0][nt] = __builtin_amdgcn_mfma_f32_16x16x32_f16(qf[0][kk], bfr, Sacc[0][nt], 0, 0, 0);
                Sacc[1][nt] = __builtin_amdgcn_mfma_f32_16x16x32_f16(qf[1][kk], bfr, Sacc[1][nt], 0, 0, 0);
            }
        }

        // ---- per mt: band mask + online softmax + P->LDS (wave-private) + PV
        _Float16* pw = &sP[(wave * 16) * PPITCH];
        for (int mt = 0; mt < 2; ++mt) {
            const int ibase = wave * 32 + mt * 16 + quad * 4;  // query row of reg r is ibase+r
            if (t != 1) {
                for (int nt = 0; nt < 8; ++nt) {
                    const int j = nt * 16 + l16;               // key col (C/D: col = lane&15)
                    for (int r = 0; r < 4; ++r) {
                        const int i = ibase + r;
                        const bool valid = (t == 0) ? (j >= i) : (j <= i);
                        if (!valid) Sacc[mt][nt][r] = -3.0e38f;
                    }
                }
            }
            float mx[4];
            for (int r = 0; r < 4; ++r) {
                mx[r] = Sacc[mt][0][r];
                for (int nt = 1; nt < 8; ++nt) mx[r] = fmaxf(mx[r], Sacc[mt][nt][r]);
            }
            for (int off = 1; off < 16; off <<= 1)
                for (int r = 0; r < 4; ++r) mx[r] = fmaxf(mx[r], __shfl_xor(mx[r], off, 16));
            float alpha[4], rs[4];
            for (int r = 0; r < 4; ++r) {
                const float mnew = fmaxf(m_i[mt][r], mx[r]);
                alpha[r] = exp2f((m_i[mt][r] - mnew) * L2E);
                m_i[mt][r] = mnew;
                rs[r] = 0.0f;
            }
            for (int nt = 0; nt < 8; ++nt) {
                for (int r = 0; r < 4; ++r) {
                    const float p = exp2f((Sacc[mt][nt][r] - m_i[mt][r]) * L2E);
                    rs[r] += p;
                    pw[(quad * 4 + r) * PPITCH + nt * 16 + l16] = (_Float16)p;
                }
            }
            for (int off = 1; off < 16; off <<= 1)
                for (int r = 0; r < 4; ++r) rs[r] += __shfl_xor(rs[r], off, 16);
            for (int r = 0; r < 4; ++r) l_i[mt][r] = l_i[mt][r] * alpha[r] + rs[r];
            for (int dt = 0; dt < 4; ++dt)
                for (int r = 0; r < 4; ++r) Oacc[mt][dt][r] *= alpha[r];

            // ---- O[mt] += P V  (wave-private sP; same-wave RAW handled by lgkmcnt)
            for (int kk = 0; kk < 4; ++kk) {
                const half8 pa = *(const half8*)&pw[l16 * PPITCH + kk * 32 + quad * 8];
                for (int dt = 0; dt < 4; ++dt) {
                    const half8 bfr = *(const half8*)&sVt[(dt * 16 + l16) * PPITCH + kk * 32 + quad * 8];
                    Oacc[mt][dt] = __builtin_amdgcn_mfma_f32_16x16x32_f16(pa, bfr, Oacc[mt][dt], 0, 0, 0);
                }
            }
        }
    }

    // ---- epilogue: O / l, store fp32
    for (int mt = 0; mt < 2; ++mt) {
        for (int r = 0; r < 4; ++r) {
            const float inv = 1.0f / l_i[mt][r];
            const int row = wave * 32 + mt * 16 + quad * 4 + r;
            float* orow = og + qbase + (size_t)row * HID;
            for (int dt = 0; dt < 4; ++dt)
                orow[dt * 16 + l16] = Oacc[mt][dt][r] * inv;
        }
    }
}

extern "C" void kernel_launch(void* const* d_in, const int* in_sizes, int n_in,
                              void* d_out, int out_size, void* d_ws, size_t ws_size,
                              hipStream_t stream) {
    const float* q = (const float*)d_in[0];
    const float* k = (const float*)d_in[1];
    const float* v = (const float*)d_in[2];
    float* out = (float*)d_out;
    dim3 grid(NCHUNK, NHEAD, 2);   // (chunk, head, batch)
    dim3 block(256);
    swa_fwd<<<grid, block, 0, stream>>>(q, k, v, out);
}

// Round 4
// 322.709 us; speedup vs baseline: 1.4874x; 1.0932x over previous
//
#include <hip/hip_runtime.h>

#define S_LEN 8192
#define HID   1024
#define NHEAD 16
#define DH    64
#define WIN   128
#define NCHUNK (S_LEN / WIN)   // 64

typedef _Float16 half8   __attribute__((ext_vector_type(8)));
typedef _Float16 half4_t __attribute__((ext_vector_type(4)));
typedef float    f32x4   __attribute__((ext_vector_type(4)));

#define QPITCH 72    // sK row pitch in f16 elems (64 + 8 pad)
#define PPITCH 136   // sVt row pitch in f16 elems (128 + 8 pad)

__global__ __launch_bounds__(256, 4)
void swa_fwd(const float* __restrict__ qg,
             const float* __restrict__ kg,
             const float* __restrict__ vg,
             float* __restrict__ og)
{
    const int c    = blockIdx.x;   // chunk
    const int h    = blockIdx.y;   // head
    const int b    = blockIdx.z;   // batch
    const int tid  = threadIdx.x;
    const int wave = tid >> 6;
    const int lane = tid & 63;
    const int l16  = lane & 15;
    const int quad = lane >> 4;

    __shared__ _Float16 sK [128 * QPITCH];   // 18432 B
    __shared__ _Float16 sVt[ 64 * PPITCH];   // 17408 B  (V transposed: [dim][key])
    // total 35840 B -> 4 blocks/CU

    const size_t qbase  = (((size_t)b * S_LEN + (size_t)c * WIN) * HID) + (size_t)h * DH;
    const size_t kvbase = (((size_t)b * S_LEN) * HID) + (size_t)h * DH;

    // ---- this wave's Q rows as B-fragments of S^T = K Q^T
    // B-frag (16x16x32): lane col n = l16 = query, k = kk*32 + quad*8 + j
    half8 qf[2][2];
    for (int mt = 0; mt < 2; ++mt) {
        const int row = wave * 32 + mt * 16 + l16;
        const float* qrow = qg + qbase + (size_t)row * HID;
        for (int kk = 0; kk < 2; ++kk) {
            const float4 a = *(const float4*)(qrow + kk * 32 + quad * 8);
            const float4 d = *(const float4*)(qrow + kk * 32 + quad * 8 + 4);
            qf[mt][kk] = (half8){ (_Float16)a.x, (_Float16)a.y, (_Float16)a.z, (_Float16)a.w,
                                  (_Float16)d.x, (_Float16)d.y, (_Float16)d.z, (_Float16)d.w };
        }
    }

    // O^T accumulators: D[row=dim quad*4+r][col=query l16], dt tiles over 64 dims
    f32x4 Oacc[2][4];
    for (int mt = 0; mt < 2; ++mt)
        for (int dt = 0; dt < 4; ++dt) Oacc[mt][dt] = (f32x4){0.f, 0.f, 0.f, 0.f};
    float m_i[2] = { -3.0e38f, -3.0e38f };
    float l_i[2] = { 0.0f, 0.0f };

    const int t0 = (c == 0)          ? 1 : 0;
    const int t1 = (c == NCHUNK - 1) ? 1 : 2;
    const float L2E = 1.44269504088896f;

    for (int t = t0; t <= t1; ++t) {
        __syncthreads();   // all waves done reading sK/sVt from previous tile
        {
            const int r0 = tid >> 4;
            const int c4 = (tid & 15) * 4;
            const size_t kb = kvbase + (size_t)(c * WIN + (t - 1) * WIN) * HID;
            for (int p = 0; p < 8; ++p) {
                const int row = p * 16 + r0;
                const float4 f = *(const float4*)(kg + kb + (size_t)row * HID + c4);
                half4_t hk = { (_Float16)f.x, (_Float16)f.y, (_Float16)f.z, (_Float16)f.w };
                *(half4_t*)&sK[row * QPITCH + c4] = hk;
                const float4 g = *(const float4*)(vg + kb + (size_t)row * HID + c4);
                sVt[(c4 + 0) * PPITCH + row] = (_Float16)g.x;
                sVt[(c4 + 1) * PPITCH + row] = (_Float16)g.y;
                sVt[(c4 + 2) * PPITCH + row] = (_Float16)g.z;
                sVt[(c4 + 3) * PPITCH + row] = (_Float16)g.w;
            }
        }
        __syncthreads();

        half4_t Pf[2][8];   // P^T fragments, feed PV directly as B-operand
        for (int mt = 0; mt < 2; ++mt) {
            // ---- S^T = K Q^T : C tile [row=key nt*16+quad*4+r][col=query l16]
            f32x4 Sacc[8];
            #pragma unroll
            for (int nt = 0; nt < 8; ++nt) Sacc[nt] = (f32x4){0.f, 0.f, 0.f, 0.f};
            #pragma unroll
            for (int kk = 0; kk < 2; ++kk) {
                #pragma unroll
                for (int nt = 0; nt < 8; ++nt) {
                    const half8 kf = *(const half8*)&sK[(nt * 16 + l16) * QPITCH + kk * 32 + quad * 8];
                    Sacc[nt] = __builtin_amdgcn_mfma_f32_16x16x32_f16(kf, qf[mt][kk], Sacc[nt], 0, 0, 0);
                }
            }

            const int iq = wave * 32 + mt * 16 + l16;   // local query index (0..127)
            if (t != 1) {
                #pragma unroll
                for (int nt = 0; nt < 8; ++nt) {
                    #pragma unroll
                    for (int r = 0; r < 4; ++r) {
                        const int j = nt * 16 + quad * 4 + r;   // local key index
                        const bool valid = (t == 0) ? (j >= iq) : (j <= iq);
                        if (!valid) Sacc[nt][r] = -3.0e38f;
                    }
                }
            }

            // ---- online softmax (scalar state per lane: query = lane col)
            float mx = Sacc[0][0];
            #pragma unroll
            for (int nt = 0; nt < 8; ++nt)
                #pragma unroll
                for (int r = 0; r < 4; ++r) mx = fmaxf(mx, Sacc[nt][r]);
            mx = fmaxf(mx, __shfl_xor(mx, 16, 64));
            mx = fmaxf(mx, __shfl_xor(mx, 32, 64));
            const float mnew = fmaxf(m_i[mt], mx);
            const float alpha = exp2f((m_i[mt] - mnew) * L2E);
            m_i[mt] = mnew;
            float rs = 0.0f;
            #pragma unroll
            for (int nt = 0; nt < 8; ++nt) {
                float p0 = exp2f((Sacc[nt][0] - mnew) * L2E);
                float p1 = exp2f((Sacc[nt][1] - mnew) * L2E);
                float p2 = exp2f((Sacc[nt][2] - mnew) * L2E);
                float p3 = exp2f((Sacc[nt][3] - mnew) * L2E);
                rs += (p0 + p1) + (p2 + p3);
                Pf[mt][nt] = (half4_t){ (_Float16)p0, (_Float16)p1, (_Float16)p2, (_Float16)p3 };
            }
            rs += __shfl_xor(rs, 16, 64);
            rs += __shfl_xor(rs, 32, 64);
            l_i[mt] = l_i[mt] * alpha + rs;
            #pragma unroll
            for (int dt = 0; dt < 4; ++dt) {
                Oacc[mt][dt][0] *= alpha; Oacc[mt][dt][1] *= alpha;
                Oacc[mt][dt][2] *= alpha; Oacc[mt][dt][3] *= alpha;
            }
        }

        // ---- O^T += V^T P^T   (16x16x16: A = V^T frag, B = P^T frag from regs)
        #pragma unroll
        for (int nt = 0; nt < 8; ++nt) {
            #pragma unroll
            for (int dt = 0; dt < 4; ++dt) {
                const half4_t vf = *(const half4_t*)&sVt[(dt * 16 + l16) * PPITCH + nt * 16 + quad * 4];
                Oacc[0][dt] = __builtin_amdgcn_mfma_f32_16x16x16f16(vf, Pf[0][nt], Oacc[0][dt], 0, 0, 0);
                Oacc[1][dt] = __builtin_amdgcn_mfma_f32_16x16x16f16(vf, Pf[1][nt], Oacc[1][dt], 0, 0, 0);
            }
        }
    }

    // ---- epilogue: O = (O^T)^T / l, float4 stores (4 contiguous dims per lane)
    for (int mt = 0; mt < 2; ++mt) {
        const float inv = 1.0f / l_i[mt];
        const int row = wave * 32 + mt * 16 + l16;          // query row
        float* orow = og + qbase + (size_t)row * HID;
        #pragma unroll
        for (int dt = 0; dt < 4; ++dt) {
            float4 o = { Oacc[mt][dt][0] * inv, Oacc[mt][dt][1] * inv,
                         Oacc[mt][dt][2] * inv, Oacc[mt][dt][3] * inv };
            *(float4*)(orow + dt * 16 + quad * 4) = o;
        }
    }
}

extern "C" void kernel_launch(void* const* d_in, const int* in_sizes, int n_in,
                              void* d_out, int out_size, void* d_ws, size_t ws_size,
                              hipStream_t stream) {
    const float* q = (const float*)d_in[0];
    const float* k = (const float*)d_in[1];
    const float* v = (const float*)d_in[2];
    float* out = (float*)d_out;
    dim3 grid(NCHUNK, NHEAD, 2);   // (chunk, head, batch)
    dim3 block(256);
    swa_fwd<<<grid, block, 0, stream>>>(q, k, v, out);
}